// Round 1
// baseline (408.014 us; speedup 1.0000x reference)
//
#include <hip/hip_runtime.h>
#include <stdint.h>

constexpr int CB  = 64;     // batches
constexpr int CN  = 2048;   // keypoints per batch
constexpr int CC  = 256;    // channels
constexpr int CNB = 100;    // base classes
constexpr int CNBP = 112;   // padded to 7*16 for MFMA n-tiles
#define EPSF 1e-12f

typedef __attribute__((ext_vector_type(8))) short short8;
typedef __attribute__((ext_vector_type(4))) float floatx4;

__device__ inline short f2bf(float f) {
  union { float f; uint32_t u; } v; v.f = f;
  uint32_t u = v.u;
  uint32_t r = u + 0x7FFFu + ((u >> 16) & 1u);   // RNE (non-NaN inputs)
  return (short)(r >> 16);
}

// ---------------- prep: Wq -> bf16 ----------------
__global__ void prep_wq_kernel(const float* __restrict__ Wq, short* __restrict__ Wqb) {
  int i = blockIdx.x * 256 + threadIdx.x;       // 256 blocks x 256 = 65536
  Wqb[i] = f2bf(Wq[i]);
}

// ---------------- prep: kn = normalize(bw @ Wk^T + bk) -> bf16, padded ----------------
__global__ void prep_kn_kernel(const float* __restrict__ bw, const float* __restrict__ Wk,
                               const float* __restrict__ bk, short* __restrict__ knb) {
  const int m = blockIdx.x;      // 0..111
  const int c = threadIdx.x;     // 0..255
  float kv = 0.0f;
  if (m < CNB) {
    const float* wr = Wk + (size_t)c * CC;
    const float* br = bw + (size_t)m * CC;
    #pragma unroll 4
    for (int j = 0; j < CC; ++j) kv += wr[j] * br[j];
    kv += bk[c];
  }
  float s = kv * kv;
  s += __shfl_xor(s, 1);  s += __shfl_xor(s, 2);  s += __shfl_xor(s, 4);
  s += __shfl_xor(s, 8);  s += __shfl_xor(s, 16); s += __shfl_xor(s, 32);
  __shared__ float red[4];
  const int wv = threadIdx.x >> 6, ln = threadIdx.x & 63;
  if (ln == 0) red[wv] = s;
  __syncthreads();
  const float tot = red[0] + red[1] + red[2] + red[3];
  const float rn = 1.0f / fmaxf(sqrtf(tot), EPSF);
  knb[(size_t)m * CC + c] = (m < CNB) ? f2bf(kv * rn) : (short)0;
}

// ---------------- main: Q = X@Wq^T, S = Q@kn^T * rnorm, softmax, partial sums ----------------
// 2048 blocks (64 b x 32 tiles of 64 rows), 256 threads = 4 waves, 16 rows/wave.
// MFMA 16x16x32 bf16 layouts (guide-verified):
//   A: lane holds A[m=lane&15][k=quad*8+j], j=0..7   (8 bf16, contiguous k)
//   B: lane holds B[k=quad*8+j][n=lane&15]           (8 bf16, contiguous k)
//   C/D: lane holds D[m=quad*4+reg][n=lane&15]       (4 f32)
__global__ __launch_bounds__(256) void main_kernel(
    const float* __restrict__ X, const float* __restrict__ mask,
    const short* __restrict__ Wqb, const float* __restrict__ bq,
    const short* __restrict__ knb,
    float* __restrict__ att_sum, float* __restrict__ x_sum, float* __restrict__ mask_sum) {
  const int b    = blockIdx.x >> 5;
  const int tile = blockIdx.x & 31;
  const int n0   = tile * 64;
  const int tid  = threadIdx.x;
  const int wave = tid >> 6;
  const int lane = tid & 63;
  const int quad = lane >> 4;
  const int l16  = lane & 15;
  const int row0 = n0 + wave * 16;

  __shared__ short qlds[4][16][264];   // bf16 Q per wave; pitch 264 -> only 2-way LDS aliasing

  // ---- phase 1: A-frags of X (fp32 -> bf16) ----
  short8 a[8];
  {
    const float* xr = X + ((size_t)b * CN + row0 + l16) * CC + quad * 8;
    #pragma unroll
    for (int kc = 0; kc < 8; ++kc) {
      const float4* p = (const float4*)(xr + kc * 32);
      float4 f0 = p[0], f1 = p[1];
      short8 t;
      t[0] = f2bf(f0.x); t[1] = f2bf(f0.y); t[2] = f2bf(f0.z); t[3] = f2bf(f0.w);
      t[4] = f2bf(f1.x); t[5] = f2bf(f1.y); t[6] = f2bf(f1.z); t[7] = f2bf(f1.w);
      a[kc] = t;
    }
  }
  // Q = X @ Wq^T + bq ; stash bf16(Q) to LDS (C-layout -> [row][col]); track row sum-of-squares
  float sumsq[4] = {0.f, 0.f, 0.f, 0.f};
  for (int nt = 0; nt < 16; ++nt) {
    floatx4 acc = {0.f, 0.f, 0.f, 0.f};
    const short* wp = Wqb + (nt * 16 + l16) * CC + quad * 8;   // B[k][n] = Wq[n][k]
    #pragma unroll
    for (int kc = 0; kc < 8; ++kc) {
      short8 bf = *(const short8*)(wp + kc * 32);
      acc = __builtin_amdgcn_mfma_f32_16x16x32_bf16(a[kc], bf, acc, 0, 0, 0);
    }
    const float bqv = bq[nt * 16 + l16];
    #pragma unroll
    for (int r = 0; r < 4; ++r) {
      float q = acc[r] + bqv;
      sumsq[r] += q * q;
      qlds[wave][quad * 4 + r][nt * 16 + l16] = f2bf(q);
    }
  }
  float rnorm[4];
  #pragma unroll
  for (int r = 0; r < 4; ++r) {
    float s = sumsq[r];
    s += __shfl_xor(s, 1); s += __shfl_xor(s, 2);
    s += __shfl_xor(s, 4); s += __shfl_xor(s, 8);
    rnorm[r] = 1.0f / fmaxf(sqrtf(s), EPSF);   // applied to S, not to q (norm commutes)
  }

  // ---- phase 2: A-frags of Q from LDS (layout transpose), S = Q @ kn^T ----
  short8 qa[8];
  #pragma unroll
  for (int kc = 0; kc < 8; ++kc)
    qa[kc] = *(const short8*)&qlds[wave][l16][kc * 32 + quad * 8];

  floatx4 sacc[7];
  #pragma unroll
  for (int nt = 0; nt < 7; ++nt) {
    floatx4 acc = {0.f, 0.f, 0.f, 0.f};
    const short* kp = knb + (nt * 16 + l16) * CC + quad * 8;   // B[k][n] = kn[n][k]
    #pragma unroll
    for (int kc = 0; kc < 8; ++kc) {
      short8 bf = *(const short8*)(kp + kc * 32);
      acc = __builtin_amdgcn_mfma_f32_16x16x32_bf16(qa[kc], bf, acc, 0, 0, 0);
    }
    sacc[nt] = acc;
  }

  // ---- softmax over m (|s|<=1 so no max-subtraction needed) + masked accumulation ----
  float mw[4];
  #pragma unroll
  for (int r = 0; r < 4; ++r)
    mw[r] = mask[(size_t)b * CN + row0 + quad * 4 + r];

  const bool v6 = (l16 < 4);               // tile 6 covers m=96..111; valid iff m<100
  float p[7][4];
  float denom[4] = {0.f, 0.f, 0.f, 0.f};
  #pragma unroll
  for (int nt = 0; nt < 7; ++nt) {
    const bool v = (nt < 6) || v6;
    #pragma unroll
    for (int r = 0; r < 4; ++r) {
      float e = v ? __expf(sacc[nt][r] * rnorm[r]) : 0.0f;
      p[nt][r] = e;
      denom[r] += e;
    }
  }
  float wr[4];
  #pragma unroll
  for (int r = 0; r < 4; ++r) {
    float s = denom[r];
    s += __shfl_xor(s, 1); s += __shfl_xor(s, 2);
    s += __shfl_xor(s, 4); s += __shfl_xor(s, 8);
    wr[r] = mw[r] / s;                      // fold mask weight and 1/denom
  }
  #pragma unroll
  for (int nt = 0; nt < 7; ++nt) {
    float contrib = p[nt][0] * wr[0] + p[nt][1] * wr[1] + p[nt][2] * wr[2] + p[nt][3] * wr[3];
    contrib += __shfl_xor(contrib, 16);
    contrib += __shfl_xor(contrib, 32);     // sum the wave's 16 rows
    if (quad == 0)
      atomicAdd(&att_sum[b * CNBP + nt * 16 + l16], contrib);
  }

  // ---- branch 1 (fp32): masked column sums over the block's 64 rows ----
  {
    float acc = 0.0f;
    const float* xp = X + ((size_t)b * CN + n0) * CC + tid;
    const float* mp = mask + (size_t)b * CN + n0;
    #pragma unroll 8
    for (int r = 0; r < 64; ++r)
      acc += mp[r] * xp[(size_t)r * CC];    // coalesced; L2-hot (just streamed by phase 1)
    atomicAdd(&x_sum[b * CC + tid], acc);
  }
  if (wave == 0) {
    float mv = mask[(size_t)b * CN + n0 + lane];
    mv += __shfl_xor(mv, 1); mv += __shfl_xor(mv, 2); mv += __shfl_xor(mv, 4);
    mv += __shfl_xor(mv, 8); mv += __shfl_xor(mv, 16); mv += __shfl_xor(mv, 32);
    if (lane == 0) atomicAdd(&mask_sum[b], mv);
  }
}

// ---------------- final combine ----------------
__global__ void final_kernel(const float* __restrict__ bw, const float* __restrict__ w_avg,
                             const float* __restrict__ w_att,
                             const float* __restrict__ att_sum, const float* __restrict__ x_sum,
                             const float* __restrict__ mask_sum, float* __restrict__ out) {
  const int b = blockIdx.x, c = threadIdx.x;
  const float rd  = 1.0f / fmaxf(mask_sum[b], EPSF);
  const float wn1 = x_sum[b * CC + c] * rd * w_avg[c];
  float acc = 0.0f;
  #pragma unroll 4
  for (int m = 0; m < CNB; ++m)
    acc += att_sum[b * CNBP + m] * bw[(size_t)m * CC + c];
  const float wn2 = acc * rd;
  out[b * CC + c] = (wn1 + wn2 * w_att[c]) * 0.5f;
}

extern "C" void kernel_launch(void* const* d_in, const int* in_sizes, int n_in,
                              void* d_out, int out_size, void* d_ws, size_t ws_size,
                              hipStream_t stream) {
  const float* bw    = (const float*)d_in[0];
  const float* X     = (const float*)d_in[1];
  const float* mask  = (const float*)d_in[2];
  const float* Wq    = (const float*)d_in[3];
  const float* bq    = (const float*)d_in[4];
  const float* Wk    = (const float*)d_in[5];
  const float* bk    = (const float*)d_in[6];
  const float* w_avg = (const float*)d_in[7];
  const float* w_att = (const float*)d_in[8];
  float* out = (float*)d_out;

  char* ws = (char*)d_ws;
  short* Wqb     = (short*)(ws + 0);        // 131072 B
  short* knb     = (short*)(ws + 131072);   //  57344 B
  float* att_sum = (float*)(ws + 188416);   //  28672 B (64 x 112)
  float* x_sum   = (float*)(ws + 217088);   //  65536 B (64 x 256)
  float* msum    = (float*)(ws + 282624);   //    256 B (64)

  // zero the accumulators (ws is poisoned each call); region is contiguous
  hipMemsetAsync(ws + 188416, 0, 28672 + 65536 + 256, stream);

  prep_wq_kernel<<<256, 256, 0, stream>>>(Wq, Wqb);
  prep_kn_kernel<<<CNBP, 256, 0, stream>>>(bw, Wk, bk, knb);
  main_kernel<<<CB * (CN / 64), 256, 0, stream>>>(X, mask, Wqb, bq, knb, att_sum, x_sum, msum);
  final_kernel<<<CB, CC, 0, stream>>>(bw, w_avg, w_att, att_sum, x_sum, msum, out);
}